// Round 8
// baseline (666.006 us; speedup 1.0000x reference)
//
#include <hip/hip_runtime.h>

// BiMPM on MI355X. Round 17b: r17 resubmit with compile fix (non-const ref
// cannot bind to ext_vector element -> split2 writes to scalar locals).
// (1) k_proj staging: float4 loads (5 iters, 16B/lane) + packed b64 LDS
//     writes; scalar tail covers K=50's 8B-aligned rows.
// (2) k_lstm: hfp LDS round-trip dropped; h scatter-stores direct to global
//     (fire-and-forget; barrier_lds_only never drains vmcnt). r14 proved the
//     regression there was the in-place-acc/ping-pong, not the stores.
// k_branch/k_head/k_cvt byte-identical to round 16.

#define Bz 16
#define Sz 128
#define Hz 100
#define Gz 400      // 4H
#define NT 25       // Gz/16 n-tiles
#define EPSV 1e-8f

#define XIN_CH  ((long)Sz * Bz * Gz)    // 819200
#define HOUT_CH ((long)Bz * Sz * Hz)    // 204800
#define MV_CH   ((long)Bz * Sz * 120)   // 245760

typedef __attribute__((ext_vector_type(4))) float floatx4;
typedef __attribute__((ext_vector_type(8))) __bf16 bf16x8;
typedef __attribute__((ext_vector_type(2))) unsigned uintx2;

union FragU { bf16x8 v; unsigned u[4]; unsigned short s[8]; };

__device__ __forceinline__ float bf2f(unsigned short h) {
  unsigned u = ((unsigned)h) << 16;
  return __builtin_bit_cast(float, u);
}
__device__ __forceinline__ unsigned short f2bf(float x) {
  unsigned u = __builtin_bit_cast(unsigned, x);
  u = u + 0x7FFFu + ((u >> 16) & 1u);   // RNE
  return (unsigned short)(u >> 16);
}
__device__ __forceinline__ float rcpf(float x) { return __builtin_amdgcn_rcpf(x); }
__device__ __forceinline__ float sigf(float x) { return rcpf(1.0f + __expf(-x)); }
__device__ __forceinline__ float tanh_fast(float x) {
  return 1.0f - 2.0f * rcpf(__expf(2.0f * x) + 1.0f);
}

// workgroup barrier that does NOT drain vmcnt: LDS-visibility only.
__device__ __forceinline__ void barrier_lds_only() {
  __asm__ __volatile__("s_waitcnt lgkmcnt(0)\ns_barrier" ::: "memory");
}

#define MFMA(a, b, c) __builtin_amdgcn_mfma_f32_16x16x32_bf16((a), (b), (c), 0, 0, 0)

__device__ __forceinline__ int pv_chain(int grp) { return (grp < 2 ? 0 : 4) + (grp & 1); }

// hi/lo truncate-split of 2 floats packed into 2 unsigneds (hi-words)
__device__ __forceinline__ void split2(float a, float b, unsigned& hp, unsigned& lp) {
  unsigned ua = __builtin_bit_cast(unsigned, a);
  unsigned ub = __builtin_bit_cast(unsigned, b);
  hp = (ua >> 16) | (ub & 0xFFFF0000u);
  float ha = __builtin_bit_cast(float, ua & 0xFFFF0000u);
  float hb = __builtin_bit_cast(float, ub & 0xFFFF0000u);
  unsigned la = __builtin_bit_cast(unsigned, a - ha);
  unsigned lb = __builtin_bit_cast(unsigned, b - hb);
  lp = (la >> 16) | (lb & 0xFFFF0000u);
}

// ---------------- weight pre-conversion: fp32 -> bf16, permuted+padded rows ---
// dst row p (p = hidden*4+gate) = src row (p&3)*Hz + (p>>2), padded to KP.
struct CvtDesc { const float* src; unsigned short* dst; int K; int KP; };
struct Cvt6 { CvtDesc d[6]; };

__global__ __launch_bounds__(64) void k_cvt(Cvt6 C) {
  int bx = blockIdx.x;
  int m = bx / Gz;
  int p = bx % Gz;
  CvtDesc d = C.d[m];
  int orig = (p & 3) * Hz + (p >> 2);
  const float* src = d.src + (long)orig * d.K;
  unsigned short* dst = d.dst + (long)p * d.KP;
  for (int k = threadIdx.x; k < d.KP; k += 64)
    dst[k] = (k < d.K) ? f2bf(src[k]) : 0;
}

// ---------------- projection GEMM: block per (chain,t), LDS-staged tokens -----
// out[t][b][p]; W16 = pre-converted bf16, permuted rows, stride KP.
struct ProjChain {
  const int* ids;
  const float* emb;
  const float* src;
  const unsigned short* W16;  // G x KP bf16 (permuted rows, zero-padded)
  const float* bias;          // G fp32 (original order)
  float* out;                 // [t][b][p] fp32, gate-interleaved p
  int rev;
  int K;
  int nch;                    // KP/32
};
struct Proj8 { ProjChain c[8]; };

#define PPS 328   // staged token row stride in ushort

__global__ __launch_bounds__(256) void k_proj(Proj8 P) {
  __shared__ __align__(16) unsigned short phi[16 * PPS];
  __shared__ __align__(16) unsigned short plo[16 * PPS];

  int bx = blockIdx.x;
  int c = bx >> 7;
  int t = bx & 127;
  const ProjChain ch = P.c[c];
  const int K = ch.K;
  const int KP = ch.nch * 32;
  int tp = ch.rev ? (Sz - 1 - t) : t;
  int tid = threadIdx.x;

  // stage tokens: float4 loads (4x fewer latency exposures), b64 LDS writes.
  {
    const int nv = KP >> 2;
    for (int i = tid; i < 16 * nv; i += 256) {
      int b = i / nv;
      int k = (i - b * nv) << 2;
      const float* row = ch.ids ? (ch.emb + (long)ch.ids[b * Sz + tp] * K)
                                : (ch.src + ((long)b * Sz + tp) * K);
      floatx4 v;
      if (k + 3 < K) {
        v = *(const floatx4*)(row + k);
      } else {
        v[0] = (k     < K) ? row[k]     : 0.f;
        v[1] = (k + 1 < K) ? row[k + 1] : 0.f;
        v[2] = (k + 2 < K) ? row[k + 2] : 0.f;
        v[3] = (k + 3 < K) ? row[k + 3] : 0.f;
      }
      unsigned h0, l0, h1, l1;
      split2(v[0], v[1], h0, l0);
      split2(v[2], v[3], h1, l1);
      uintx2 hp, lp;
      hp[0] = h0; hp[1] = h1;
      lp[0] = l0; lp[1] = l1;
      *(uintx2*)&phi[b * PPS + k] = hp;
      *(uintx2*)&plo[b * PPS + k] = lp;
    }
  }
  __syncthreads();

  int w = tid >> 6, lane = tid & 63;
  int nl = lane & 15, qd = lane >> 4;
  floatx4 acc[7];
#pragma unroll
  for (int i = 0; i < 7; ++i) acc[i] = floatx4{0.f, 0.f, 0.f, 0.f};

  // per-tile W row bases (hoisted)
  const unsigned short* wbase[7];
#pragma unroll
  for (int i = 0; i < 7; ++i) {
    int nt = w + 4 * i;
    wbase[i] = (nt < NT) ? (ch.W16 + (long)(nt * 16 + nl) * KP) : ch.W16;
  }

  for (int cc = 0; cc < ch.nch; ++cc) {
    FragU bhi, blo;
    bhi.v = *(const bf16x8*)&phi[nl * PPS + cc * 32 + qd * 8];
    blo.v = *(const bf16x8*)&plo[nl * PPS + cc * 32 + qd * 8];
    int ko = cc * 32 + qd * 8;
#pragma unroll
    for (int i = 0; i < 7; ++i) {
      if (w + 4 * i < NT) {
        FragU whi;
        whi.v = *(const bf16x8*)(wbase[i] + ko);
        acc[i] = MFMA(whi.v, bhi.v, acc[i]);
        acc[i] = MFMA(whi.v, blo.v, acc[i]);
      }
    }
  }
#pragma unroll
  for (int i = 0; i < 7; ++i) {
    int nt = w + 4 * i;
    if (nt < NT) {
#pragma unroll
      for (int r = 0; r < 4; ++r) {
        int p = nt * 16 + qd * 4 + r;
        acc[i][r] += ch.bias[(p & 3) * Hz + (p >> 2)];
      }
      *(floatx4*)(ch.out + ((long)t * Bz + nl) * Gz + nt * 16 + qd * 4) = acc[i];
    }
  }
}

// ---------------- LSTM scan: one workgroup (16 waves) per chain ---------------
struct LstmChain {
  const float* xin;     // [t][b][p] gate-interleaved
  const float* Whh;     // G x H fp32 (original row order)
  float* hout;          // B x S x H fp32
  int rev;
  int store_all;
};
struct Lstm8 { LstmChain c[8]; };

#define NW 16     // waves per block
#define TPW 2     // max tiles per wave; tile = i*NW + w
#define NCH 4     // K chunks of 32 (K=128 padded, valid 100)
#define HPR 136   // plane row stride in halfwords (272B; 4(nl+qd) mod 32 even)

__global__ __launch_bounds__(1024, 4) void k_lstm(Lstm8 P) {
  __shared__ __align__(16) unsigned short hhi[2][Bz * HPR];  // bf16 hi plane
  __shared__ __align__(16) unsigned short hlo[2][Bz * HPR];  // bf16 lo plane

  const LstmChain ch = P.c[blockIdx.x];
  const int tid = threadIdx.x;
  const int w = tid >> 6;
  const int lane = tid & 63;
  const int nl = lane & 15;
  const int qd = lane >> 4;

  // zero both planes (padding k=100..127 stays 0 forever)
  for (int i = tid; i < Bz * HPR; i += 1024) {
    ((unsigned*)hhi)[i] = 0;
    ((unsigned*)hlo)[i] = 0;
  }
  __syncthreads();

  // Whh fragments: plain bf16, k = cc*32 + qd*8 + j (k_proj layout)
  FragU wa[TPW][NCH];
#pragma unroll
  for (int i = 0; i < TPW; ++i) {
    int tile = i * NW + w;
    if (tile < NT) {
      int pA = tile * 16 + nl;
      const float* wr = ch.Whh + (long)((pA & 3) * Hz + (pA >> 2)) * Hz;
#pragma unroll
      for (int cc = 0; cc < NCH; ++cc) {
#pragma unroll
        for (int j = 0; j < 8; ++j) {
          int k = cc * 32 + qd * 8 + j;
          wa[i][cc].s[j] = f2bf((k < Hz) ? wr[k] : 0.f);
        }
      }
    }
  }

  // direct global h store: hout[b][s][hd]; per-lane part hoisted, s walked
  // by uniform sdelta.
  long ploff[TPW];
#pragma unroll
  for (int i = 0; i < TPW; ++i)
    ploff[i] = (long)nl * Sz * Hz + (i * NW + w) * 4 + qd;
  const int sdelta = ch.rev ? -Hz : Hz;
  float* hrow = ch.hout + (ch.rev ? (long)(Sz - 1) * Hz : 0);
  const int store_all = ch.store_all;

  floatx4 xc[TPW], xn[TPW];
  float cstate[TPW];
#pragma unroll
  for (int i = 0; i < TPW; ++i) {
    cstate[i] = 0.f;
    xc[i] = floatx4{0.f, 0.f, 0.f, 0.f};
    if (i * NW + w < NT)
      xc[i] = *(const floatx4*)(ch.xin + (long)nl * Gz + (i * NW + w) * 16 + qd * 4);
  }

  for (int t = 0; t < Sz; ++t) {
    if (t + 1 < Sz) {
      const float* xp = ch.xin + (long)(t + 1) * Bz * Gz + (long)nl * Gz;
#pragma unroll
      for (int i = 0; i < TPW; ++i)
        if (i * NW + w < NT)
          xn[i] = *(const floatx4*)(xp + (i * NW + w) * 16 + qd * 4);
    }
    const int rp = t & 1;
    floatx4 acc[TPW];
#pragma unroll
    for (int i = 0; i < TPW; ++i) acc[i] = xc[i];
#pragma unroll
    for (int cc = 0; cc < NCH; ++cc) {
      FragU bhi, blo;
      bhi.v = *(const bf16x8*)(&hhi[rp][nl * HPR + cc * 32 + qd * 8]);
      blo.v = *(const bf16x8*)(&hlo[rp][nl * HPR + cc * 32 + qd * 8]);
#pragma unroll
      for (int i = 0; i < TPW; ++i)
        if (i * NW + w < NT) {
          acc[i] = MFMA(wa[i][cc].v, bhi.v, acc[i]);
          acc[i] = MFMA(wa[i][cc].v, blo.v, acc[i]);
        }
    }
    const int wp = rp ^ 1;
    const bool keep = store_all || (t == Sz - 1);
#pragma unroll
    for (int i = 0; i < TPW; ++i) {
      int tile = i * NW + w;
      if (tile < NT) {
        float cn = sigf(acc[i][1]) * cstate[i] + sigf(acc[i][0]) * tanh_fast(acc[i][2]);
        float h = sigf(acc[i][3]) * tanh_fast(cn);
        cstate[i] = cn;
        int hd = tile * 4 + qd;
        // truncate-split: hi = top 16 bits, lo = exact residual (bf16-trunc)
        unsigned u = __builtin_bit_cast(unsigned, h);
        float hi = __builtin_bit_cast(float, u & 0xFFFF0000u);
        unsigned ul = __builtin_bit_cast(unsigned, h - hi);
        hhi[wp][nl * HPR + hd] = (unsigned short)(u >> 16);
        hlo[wp][nl * HPR + hd] = (unsigned short)(ul >> 16);
        if (keep) hrow[ploff[i]] = h;   // fire-and-forget scatter store
      }
    }
    barrier_lds_only();
    hrow += sdelta;
#pragma unroll
    for (int i = 0; i < TPW; ++i) xc[i] = xn[i];
  }
}

// ---------------- fused branch: att + feats + match, one kernel ---------------
#define PVS2 102   // padded row stride (floats)
#define FS 104     // feat scratch stride

struct BranchArgs {
  const float* houtA;
  float* mv;
  const float* w_full[4];
  const float* w3; const float* w4; const float* w5; const float* w6;
};

__global__ __launch_bounds__(512, 1) void k_branch(BranchArgs G) {
  __shared__ float pvs[128 * PVS2];
  __shared__ float hvs[128 * PVS2 + 32];   // +pad: feats j+64 lane overread
  __shared__ float wl[60 * PVS2];
  __shared__ float attw[8 * 128];
  __shared__ float fmean[8 * FS];
  __shared__ float fmax[8 * FS];
  __shared__ float nrmp[128], nrmh[128];

  int bx = blockIdx.x;
  int grp = bx >> 6;
  int b = (bx >> 2) & 15;
  int side = (bx >> 1) & 1;
  int rh = bx & 1;
  int fw = !(grp & 1);
  int word = grp < 2;
  int pc = pv_chain(grp);
  const float* PV = G.houtA + (long)pc * HOUT_CH + (long)b * Sz * Hz;
  const float* HV = G.houtA + (long)(pc + 2) * HOUT_CH + (long)b * Sz * Hz;
  int tid = threadIdx.x;
  int w = tid >> 6, lane = tid & 63;

  for (int i = tid; i < 128 * Hz; i += 512) {
    int r = i / Hz, c = i % Hz;
    pvs[r * PVS2 + c] = PV[r * Hz + c];
    hvs[r * PVS2 + c] = HV[r * Hz + c];
  }
  {
    const float* wm = fw ? G.w3 : G.w4;
    const float* wx = fw ? G.w5 : G.w6;
    const float* wf = G.w_full[grp];
    for (int i = tid; i < 60 * Hz; i += 512) {
      int row = i / Hz, c = i % Hz;
      const float* src = (row < 20) ? wf : (row < 40 ? wm : wx);
      int rr = (row < 20) ? row : (row < 40 ? row - 20 : row - 40);
      wl[row * PVS2 + c] = src[rr * Hz + c];
    }
  }
  __syncthreads();
  if (tid < 256) {
    const float* base = (tid < 128) ? pvs : hvs;
    int r = tid & 127;
    float s = 0.f;
    for (int j = 0; j < Hz; ++j) { float v = base[r * PVS2 + j]; s += v * v; }
    if (tid < 128) nrmp[r] = sqrtf(s); else nrmh[r] = sqrtf(s);
  }
  __syncthreads();

  const float* A  = side ? hvs : pvs;
  const float* B  = side ? pvs : hvs;
  const float* nA = side ? nrmh : nrmp;
  const float* nB = side ? nrmp : nrmh;
  int bcrow = fw ? (Sz - 1) : 0;
  float* mvout = G.mv + (long)((word ? 0 : 2) + side) * MV_CH + (long)b * Sz * 120;
  int off = fw ? 0 : 60;
  int type = lane / 20;
  const float* wrow = wl + lane * PVS2;
  float* myatt = attw + w * 128;
  float* myfm = fmean + w * FS;
  float* myfx = fmax + w * FS;

  for (int task = w; task < 64; task += 8) {
    int r = rh * 64 + task;
    const float* ar = A + r * PVS2;
    float d0 = 0.f, d1 = 0.f;
    const float* b0 = B + lane * PVS2;
    const float* b1 = B + (lane + 64) * PVS2;
    for (int j = 0; j < Hz; j += 2) {
      float2 a2 = *(const float2*)(ar + j);
      float2 p2 = *(const float2*)(b0 + j);
      float2 q2 = *(const float2*)(b1 + j);
      d0 += a2.x * p2.x + a2.y * p2.y;
      d1 += a2.x * q2.x + a2.y * q2.y;
    }
    float at0 = d0 * rcpf(fmaxf(nA[r] * nB[lane], EPSV));
    float at1 = d1 * rcpf(fmaxf(nA[r] * nB[lane + 64], EPSV));
    myatt[lane] = at0;
    myatt[lane + 64] = at1;
    float s = at0 + at1;
#pragma unroll
    for (int m = 1; m < 64; m <<= 1) s += __shfl_xor(s, m);
    float inv = rcpf(fmaxf(s, EPSV));
    float m0 = 0.f, m1 = 0.f, x0 = -1e30f, x1 = -1e30f;
    const float* bj0 = B + lane;
    const float* bj1 = B + lane + 64;
    for (int q = 0; q < 128; ++q) {
      float aq = myatt[q];
      float v0 = bj0[q * PVS2];
      float v1 = bj1[q * PVS2];
      m0 += aq * v0; x0 = fmaxf(x0, aq * v0);
      m1 += aq * v1; x1 = fmaxf(x1, aq * v1);
    }
    myfm[lane] = m0 * inv;
    myfx[lane] = x0;
    if (lane < Hz - 64) { myfm[lane + 64] = m1 * inv; myfx[lane + 64] = x1; }
    if (lane < 60) {
      const float* v2p = (type == 0) ? (B + bcrow * PVS2)
                       : (type == 1) ? myfm : myfx;
      float num = 0.f, n1 = 0.f, n2 = 0.f;
      for (int j = 0; j < Hz; j += 2) {
        float2 w2 = *(const float2*)(wrow + j);
        float2 a2 = *(const float2*)(ar + j);
        float2 c2 = *(const float2*)(v2p + j);
        float ws0 = w2.x * w2.x, ws1 = w2.y * w2.y;
        num += ws0 * a2.x * c2.x + ws1 * a2.y * c2.y;
        n1  += ws0 * a2.x * a2.x + ws1 * a2.y * a2.y;
        n2  += ws0 * c2.x * c2.x + ws1 * c2.y * c2.y;
      }
      mvout[r * 120 + off + lane] = num * rcpf(fmaxf(sqrtf(n1) * sqrtf(n2), EPSV));
    }
  }
}

// ---------------- fused head: wave-per-output GEMVs, coalesced ----------------
__global__ __launch_bounds__(1024) void k_head(const float* houtB,
                                               const float* lw, const float* lb,
                                               const float* gw, const float* gb,
                                               const float* f1w, const float* f1b,
                                               const float* f2w, const float* f2b,
                                               float* out) {
  int b = blockIdx.x;
  __shared__ float xr[800];
  __shared__ float hwv[800];
  __shared__ float f1[200];
  int tid = threadIdx.x;
  int w = tid >> 6, lane = tid & 63;
  if (tid < 800) {
    int seq = tid / Gz;
    int i = tid % Gz;
    int seg = i / Hz, j = i % Hz;
    int chain = seq * 4 + seg;
    int s_sel = (seg & 1) ? 0 : (Sz - 1);
    xr[tid] = houtB[((long)chain * Bz + b) * Sz * Hz + (long)s_sel * Hz + j];
  }
  __syncthreads();
  // phase 1: highway. wave per output op (800 = 16 waves x 50). Lanes split
  // K=400 with consecutive-4B reads (coalesced 256B/wave-inst), tree-reduce.
  for (int i = 0; i < 50; ++i) {
    int op = w + 16 * i;              // 0..799
    int seq = op >= Gz;
    int o = op - seq * Gz;
    const float* lwr = lw + (long)o * Gz;
    const float* gwr = gw + (long)o * Gz;
    const float* xs = xr + seq * Gz;
    float al = 0.f, ag = 0.f;
#pragma unroll
    for (int j = 0; j < 7; ++j) {     // 6*64 + 16 = 400
      int k = lane + 64 * j;
      if (j < 6 || lane < 16) {
        float x = xs[k];
        al += x * lwr[k];
        ag += x * gwr[k];
      }
    }
#pragma unroll
    for (int m = 1; m < 64; m <<= 1) {
      al += __shfl_xor(al, m);
      ag += __shfl_xor(ag, m);
    }
    if (lane == 0) {
      al += lb[o];
      ag += gb[o];
      float hlin = fmaxf(al, 0.f);
      float tg = sigf(ag);
      hwv[op] = tg * hlin + (1.f - tg) * xr[op];
    }
  }
  __syncthreads();
  // phase 2: fc1 (200 outputs, K=800 = 12*64 + 32)
  for (int i = 0; i < 13; ++i) {
    int o = w + 16 * i;
    if (o < 200) {
      const float* wr = f1w + (long)o * 800;
      float acc = 0.f;
#pragma unroll
      for (int j = 0; j < 13; ++j) {
        int k = lane + 64 * j;
        if (j < 12 || lane < 32) acc += hwv[k] * wr[k];
      }
#pragma unroll
      for (int m = 1; m < 64; m <<= 1) acc += __shfl_xor(acc, m);
      if (lane == 0) f1[o] = tanh_fast(acc + f1b[o]);
    }
  }
  __syncthreads();
  // phase 3: fc2 (3 outputs, K=200 = 3*64 + 8)
  if (w < 3) {
    const float* wr = f2w + w * 200;
    float acc = 0.f;
#pragma unroll
    for (int j = 0; j < 4; ++j) {
      int k = lane + 64 * j;
      if (j < 3 || lane < 8) acc += f1[k] * wr[k];
    }
#pragma unroll
    for (int m = 1; m < 64; m <<= 1) acc += __shfl_xor(acc, m);
    if (lane == 0) out[b * 3 + w] = acc + f2b[w];
  }
}

// ---------------- host orchestration -----------------------------------------
extern "C" void kernel_launch(void* const* d_in, const int* in_sizes, int n_in,
                              void* d_out, int out_size, void* d_ws, size_t ws_size,
                              hipStream_t stream) {
  (void)in_sizes; (void)n_in; (void)out_size;

  const int* p_ids  = (const int*)d_in[0];
  const int* h_ids  = (const int*)d_in[1];
  const int* cp_ids = (const int*)d_in[2];
  const int* ch_ids = (const int*)d_in[3];
  const float* word_emb = (const float*)d_in[4];
  const float* char_emb = (const float*)d_in[5];
  const float* ctx_Wih_f = (const float*)d_in[6];
  const float* ctx_Whh_f = (const float*)d_in[7];
  const float* ctx_b_f   = (const float*)d_in[8];
  const float* ctx_Wih_b = (const float*)d_in[9];
  const float* ctx_Whh_b = (const float*)d_in[10];
  const float* ctx_b_b   = (const float*)d_in[11];
  const float* chr_Wih_f = (const float*)d_in[12];
  const float* chr_Whh_f = (const float*)d_in[13];
  const float* chr_b_f   = (const float*)d_in[14];
  const float* chr_Wih_b = (const float*)d_in[15];
  const float* chr_Whh_b = (const float*)d_in[16];
  const float* chr_b_b   = (const float*)d_in[17];
  const float* agg_Wih_f = (const float*)d_in[18];
  const float* agg_Whh_f = (const float*)d_in[19];
  const float* agg_b_f   = (const float*)d_in[20];
  const float* agg_Wih_b = (const float*)d_in[21];
  const float* agg_Whh_b = (const float*)d_in[22];
  const float* agg_b_b   = (const float*)d_in[23];
  const float* mp_w1 = (const float*)d_in[24];
  const float* mp_w2 = (const float*)d_in[25];
  const float* mp_w3 = (const float*)d_in[26];
  const float* mp_w4 = (const float*)d_in[27];
  const float* mp_w5 = (const float*)d_in[28];
  const float* mp_w6 = (const float*)d_in[29];
  const float* char_w1 = (const float*)d_in[30];
  const float* char_w2 = (const float*)d_in[31];
  const float* hw_lin_w  = (const float*)d_in[32];
  const float* hw_lin_b  = (const float*)d_in[33];
  const float* hw_gate_w = (const float*)d_in[34];
  const float* hw_gate_b = (const float*)d_in[35];
  const float* fc1_w = (const float*)d_in[36];
  const float* fc1_b = (const float*)d_in[37];
  const float* fc2_w = (const float*)d_in[38];
  const float* fc2_b = (const float*)d_in[39];

  float* ws = (float*)d_ws;
  float* XIN    = ws;                         // 8 * XIN_CH (reused A -> B)
  float* HOUT_A = XIN + 8 * XIN_CH;
  float* HOUT_B = HOUT_A + 8 * HOUT_CH;
  float* MV     = HOUT_B + 8 * HOUT_CH;
  unsigned short* WC = (unsigned short*)(MV + 4 * MV_CH);
  // bf16 W buffers: ctx f/b (KP=320), chr f/b (KP=64), agg f/b (KP=128)
  unsigned short* W_ctx_f = WC;
  unsigned short* W_ctx_b = W_ctx_f + (long)Gz * 320;
  unsigned short* W_chr_f = W_ctx_b + (long)Gz * 320;
  unsigned short* W_chr_b = W_chr_f + (long)Gz * 64;
  unsigned short* W_agg_f = W_chr_b + (long)Gz * 64;
  unsigned short* W_agg_b = W_agg_f + (long)Gz * 128;
  size_t needed = (size_t)((char*)(W_agg_b + (long)Gz * 128) - (char*)ws);
  if (ws_size < needed) return;

  // ---- 0. weight pre-conversion ----
  {
    Cvt6 cv{};
    cv.d[0] = {ctx_Wih_f, W_ctx_f, 300, 320};
    cv.d[1] = {ctx_Wih_b, W_ctx_b, 300, 320};
    cv.d[2] = {chr_Wih_f, W_chr_f, 50, 64};
    cv.d[3] = {chr_Wih_b, W_chr_b, 50, 64};
    cv.d[4] = {agg_Wih_f, W_agg_f, 120, 128};
    cv.d[5] = {agg_Wih_b, W_agg_b, 120, 128};
    k_cvt<<<6 * Gz, 64, 0, stream>>>(cv);
  }
  // ---- 1. fused phase-A projections (block per (chain,t)) ----
  {
    Proj8 pc{};
    const int* idv[8] = {p_ids, p_ids, h_ids, h_ids, cp_ids, cp_ids, ch_ids, ch_ids};
    for (int c = 0; c < 8; ++c) {
      int word = c < 4;
      pc.c[c].ids = idv[c];
      pc.c[c].emb = word ? word_emb : char_emb;
      pc.c[c].src = nullptr;
      pc.c[c].W16  = word ? ((c & 1) ? W_ctx_b : W_ctx_f) : ((c & 1) ? W_chr_b : W_chr_f);
      pc.c[c].bias = word ? ((c & 1) ? ctx_b_b : ctx_b_f) : ((c & 1) ? chr_b_b : chr_b_f);
      pc.c[c].out = XIN + c * XIN_CH;
      pc.c[c].rev = c & 1;
      pc.c[c].K = word ? 300 : 50;
      pc.c[c].nch = word ? 10 : 2;
    }
    k_proj<<<8 * Sz, 256, 0, stream>>>(pc);
  }
  // ---- 2. phase-A LSTMs ----
  {
    Lstm8 la{};
    for (int c = 0; c < 8; ++c) {
      la.c[c].xin = XIN + c * XIN_CH;
      la.c[c].Whh = (c < 4) ? ((c & 1) ? ctx_Whh_b : ctx_Whh_f)
                            : ((c & 1) ? chr_Whh_b : chr_Whh_f);
      la.c[c].hout = HOUT_A + c * HOUT_CH;
      la.c[c].rev = c & 1;
      la.c[c].store_all = 1;
    }
    k_lstm<<<8, 1024, 0, stream>>>(la);
  }
  // ---- 3. fused branch ----
  {
    BranchArgs g{};
    g.houtA = HOUT_A; g.mv = MV;
    g.w_full[0] = mp_w1; g.w_full[1] = mp_w2; g.w_full[2] = char_w1; g.w_full[3] = char_w2;
    g.w3 = mp_w3; g.w4 = mp_w4; g.w5 = mp_w5; g.w6 = mp_w6;
    k_branch<<<256, 512, 0, stream>>>(g);
  }
  // ---- 4. phase-B projections (K=120) ----
  {
    Proj8 pa{};
    for (int c = 0; c < 8; ++c) {
      pa.c[c].ids = nullptr; pa.c[c].emb = nullptr;
      pa.c[c].src = MV + (c >> 1) * MV_CH;
      pa.c[c].W16 = (c & 1) ? W_agg_b : W_agg_f;
      pa.c[c].bias = (c & 1) ? agg_b_b : agg_b_f;
      pa.c[c].out = XIN + c * XIN_CH;
      pa.c[c].rev = c & 1;
      pa.c[c].K = 120;
      pa.c[c].nch = 4;
    }
    k_proj<<<8 * Sz, 256, 0, stream>>>(pa);
  }
  // ---- 5. phase-B LSTMs ----
  {
    Lstm8 la{};
    for (int c = 0; c < 8; ++c) {
      la.c[c].xin = XIN + c * XIN_CH;
      la.c[c].Whh = (c & 1) ? agg_Whh_b : agg_Whh_f;
      la.c[c].hout = HOUT_B + c * HOUT_CH;
      la.c[c].rev = c & 1;
      la.c[c].store_all = 0;
    }
    k_lstm<<<8, 1024, 0, stream>>>(la);
  }
  // ---- 6. fused head ----
  k_head<<<Bz, 1024, 0, stream>>>(HOUT_B, hw_lin_w, hw_lin_b, hw_gate_w, hw_gate_b,
                                  fc1_w, fc1_b, fc2_w, fc2_b, (float*)d_out);
}

// Round 9
// 626.056 us; speedup vs baseline: 1.0638x; 1.0638x over previous
//
#include <hip/hip_runtime.h>

// BiMPM on MI355X. Round 18: recombine proven-best parts. r17b taught:
// direct scatter h-stores REGRESS k_lstm +20us/dispatch (16 cachelines per
// wave-store through TA vs 2 for hfp-staged coalesced stores; the hfp LDS
// round-trip buys store coalescing). k_proj float4 staging gained ~7us.
// So: k_lstm = r16 byte-identical (hfp staging); k_proj = r17b float4
// staging. k_branch/k_head/k_cvt byte-identical to r16.

#define Bz 16
#define Sz 128
#define Hz 100
#define Gz 400      // 4H
#define NT 25       // Gz/16 n-tiles
#define EPSV 1e-8f

#define XIN_CH  ((long)Sz * Bz * Gz)    // 819200
#define HOUT_CH ((long)Bz * Sz * Hz)    // 204800
#define MV_CH   ((long)Bz * Sz * 120)   // 245760

typedef __attribute__((ext_vector_type(4))) float floatx4;
typedef __attribute__((ext_vector_type(8))) __bf16 bf16x8;
typedef __attribute__((ext_vector_type(2))) unsigned uintx2;

union FragU { bf16x8 v; unsigned u[4]; unsigned short s[8]; };

__device__ __forceinline__ float bf2f(unsigned short h) {
  unsigned u = ((unsigned)h) << 16;
  return __builtin_bit_cast(float, u);
}
__device__ __forceinline__ unsigned short f2bf(float x) {
  unsigned u = __builtin_bit_cast(unsigned, x);
  u = u + 0x7FFFu + ((u >> 16) & 1u);   // RNE
  return (unsigned short)(u >> 16);
}
__device__ __forceinline__ float rcpf(float x) { return __builtin_amdgcn_rcpf(x); }
__device__ __forceinline__ float sigf(float x) { return rcpf(1.0f + __expf(-x)); }
__device__ __forceinline__ float tanh_fast(float x) {
  return 1.0f - 2.0f * rcpf(__expf(2.0f * x) + 1.0f);
}

// workgroup barrier that does NOT drain vmcnt: LDS-visibility only.
__device__ __forceinline__ void barrier_lds_only() {
  __asm__ __volatile__("s_waitcnt lgkmcnt(0)\ns_barrier" ::: "memory");
}

#define MFMA(a, b, c) __builtin_amdgcn_mfma_f32_16x16x32_bf16((a), (b), (c), 0, 0, 0)

__device__ __forceinline__ int pv_chain(int grp) { return (grp < 2 ? 0 : 4) + (grp & 1); }

// hi/lo truncate-split of 2 floats packed into 2 unsigneds (hi-words)
__device__ __forceinline__ void split2(float a, float b, unsigned& hp, unsigned& lp) {
  unsigned ua = __builtin_bit_cast(unsigned, a);
  unsigned ub = __builtin_bit_cast(unsigned, b);
  hp = (ua >> 16) | (ub & 0xFFFF0000u);
  float ha = __builtin_bit_cast(float, ua & 0xFFFF0000u);
  float hb = __builtin_bit_cast(float, ub & 0xFFFF0000u);
  unsigned la = __builtin_bit_cast(unsigned, a - ha);
  unsigned lb = __builtin_bit_cast(unsigned, b - hb);
  lp = (la >> 16) | (lb & 0xFFFF0000u);
}

// ---------------- weight pre-conversion: fp32 -> bf16, permuted+padded rows ---
// dst row p (p = hidden*4+gate) = src row (p&3)*Hz + (p>>2), padded to KP.
struct CvtDesc { const float* src; unsigned short* dst; int K; int KP; };
struct Cvt6 { CvtDesc d[6]; };

__global__ __launch_bounds__(64) void k_cvt(Cvt6 C) {
  int bx = blockIdx.x;
  int m = bx / Gz;
  int p = bx % Gz;
  CvtDesc d = C.d[m];
  int orig = (p & 3) * Hz + (p >> 2);
  const float* src = d.src + (long)orig * d.K;
  unsigned short* dst = d.dst + (long)p * d.KP;
  for (int k = threadIdx.x; k < d.KP; k += 64)
    dst[k] = (k < d.K) ? f2bf(src[k]) : 0;
}

// ---------------- projection GEMM: block per (chain,t), LDS-staged tokens -----
// out[t][b][p]; W16 = pre-converted bf16, permuted rows, stride KP.
struct ProjChain {
  const int* ids;
  const float* emb;
  const float* src;
  const unsigned short* W16;  // G x KP bf16 (permuted rows, zero-padded)
  const float* bias;          // G fp32 (original order)
  float* out;                 // [t][b][p] fp32, gate-interleaved p
  int rev;
  int K;
  int nch;                    // KP/32
};
struct Proj8 { ProjChain c[8]; };

#define PPS 328   // staged token row stride in ushort

__global__ __launch_bounds__(256) void k_proj(Proj8 P) {
  __shared__ __align__(16) unsigned short phi[16 * PPS];
  __shared__ __align__(16) unsigned short plo[16 * PPS];

  int bx = blockIdx.x;
  int c = bx >> 7;
  int t = bx & 127;
  const ProjChain ch = P.c[c];
  const int K = ch.K;
  const int KP = ch.nch * 32;
  int tp = ch.rev ? (Sz - 1 - t) : t;
  int tid = threadIdx.x;

  // stage tokens: float4 loads (4x fewer latency exposures), b64 LDS writes.
  {
    const int nv = KP >> 2;
    for (int i = tid; i < 16 * nv; i += 256) {
      int b = i / nv;
      int k = (i - b * nv) << 2;
      const float* row = ch.ids ? (ch.emb + (long)ch.ids[b * Sz + tp] * K)
                                : (ch.src + ((long)b * Sz + tp) * K);
      floatx4 v;
      if (k + 3 < K) {
        v = *(const floatx4*)(row + k);
      } else {
        v[0] = (k     < K) ? row[k]     : 0.f;
        v[1] = (k + 1 < K) ? row[k + 1] : 0.f;
        v[2] = (k + 2 < K) ? row[k + 2] : 0.f;
        v[3] = (k + 3 < K) ? row[k + 3] : 0.f;
      }
      unsigned h0, l0, h1, l1;
      split2(v[0], v[1], h0, l0);
      split2(v[2], v[3], h1, l1);
      uintx2 hp, lp;
      hp[0] = h0; hp[1] = h1;
      lp[0] = l0; lp[1] = l1;
      *(uintx2*)&phi[b * PPS + k] = hp;
      *(uintx2*)&plo[b * PPS + k] = lp;
    }
  }
  __syncthreads();

  int w = tid >> 6, lane = tid & 63;
  int nl = lane & 15, qd = lane >> 4;
  floatx4 acc[7];
#pragma unroll
  for (int i = 0; i < 7; ++i) acc[i] = floatx4{0.f, 0.f, 0.f, 0.f};

  // per-tile W row bases (hoisted)
  const unsigned short* wbase[7];
#pragma unroll
  for (int i = 0; i < 7; ++i) {
    int nt = w + 4 * i;
    wbase[i] = (nt < NT) ? (ch.W16 + (long)(nt * 16 + nl) * KP) : ch.W16;
  }

  for (int cc = 0; cc < ch.nch; ++cc) {
    FragU bhi, blo;
    bhi.v = *(const bf16x8*)&phi[nl * PPS + cc * 32 + qd * 8];
    blo.v = *(const bf16x8*)&plo[nl * PPS + cc * 32 + qd * 8];
    int ko = cc * 32 + qd * 8;
#pragma unroll
    for (int i = 0; i < 7; ++i) {
      if (w + 4 * i < NT) {
        FragU whi;
        whi.v = *(const bf16x8*)(wbase[i] + ko);
        acc[i] = MFMA(whi.v, bhi.v, acc[i]);
        acc[i] = MFMA(whi.v, blo.v, acc[i]);
      }
    }
  }
#pragma unroll
  for (int i = 0; i < 7; ++i) {
    int nt = w + 4 * i;
    if (nt < NT) {
#pragma unroll
      for (int r = 0; r < 4; ++r) {
        int p = nt * 16 + qd * 4 + r;
        acc[i][r] += ch.bias[(p & 3) * Hz + (p >> 2)];
      }
      *(floatx4*)(ch.out + ((long)t * Bz + nl) * Gz + nt * 16 + qd * 4) = acc[i];
    }
  }
}

// ---------------- LSTM scan: one workgroup (16 waves) per chain ---------------
struct LstmChain {
  const float* xin;     // [t][b][p] gate-interleaved
  const float* Whh;     // G x H fp32 (original row order)
  float* hout;          // B x S x H fp32
  int rev;
  int store_all;
};
struct Lstm8 { LstmChain c[8]; };

#define NW 16     // waves per block
#define TPW 2     // max tiles per wave; tile = i*NW + w
#define NCH 4     // K chunks of 32 (K=128 padded, valid 100)
#define HPR 136   // plane row stride in halfwords (272B; 4(nl+qd) mod 32 even)

__global__ __launch_bounds__(1024, 4) void k_lstm(Lstm8 P) {
  __shared__ __align__(16) unsigned short hhi[2][Bz * HPR];  // bf16 hi plane
  __shared__ __align__(16) unsigned short hlo[2][Bz * HPR];  // bf16 lo plane
  __shared__ float hfp[2][Bz * Hz];                          // fp32 h stage

  const LstmChain ch = P.c[blockIdx.x];
  const int tid = threadIdx.x;
  const int w = tid >> 6;
  const int lane = tid & 63;
  const int nl = lane & 15;
  const int qd = lane >> 4;

  // zero both planes (padding k=100..127 stays 0 forever)
  for (int i = tid; i < Bz * HPR; i += 1024) {
    ((unsigned*)hhi)[i] = 0;
    ((unsigned*)hlo)[i] = 0;
  }
  __syncthreads();

  // Whh fragments: plain bf16, k = cc*32 + qd*8 + j (k_proj layout)
  FragU wa[TPW][NCH];
#pragma unroll
  for (int i = 0; i < TPW; ++i) {
    int tile = i * NW + w;
    if (tile < NT) {
      int pA = tile * 16 + nl;
      const float* wr = ch.Whh + (long)((pA & 3) * Hz + (pA >> 2)) * Hz;
#pragma unroll
      for (int cc = 0; cc < NCH; ++cc) {
#pragma unroll
        for (int j = 0; j < 8; ++j) {
          int k = cc * 32 + qd * 8 + j;
          wa[i][cc].s[j] = f2bf((k < Hz) ? wr[k] : 0.f);
        }
      }
    }
  }

  // hout store addressing hoisted (idx = tid + it*1024)
  long hbase[2]; int hok[2]; int hidx[2];
#pragma unroll
  for (int it = 0; it < 2; ++it) {
    int idx = tid + it * 1024;
    hok[it] = idx < Bz * Hz;
    int bq = idx / Hz, rq = idx - bq * Hz;
    hbase[it] = (long)bq * Sz * Hz + rq;
    hidx[it] = idx;
  }

  floatx4 xc[TPW], xn[TPW];
  float cstate[TPW];
#pragma unroll
  for (int i = 0; i < TPW; ++i) {
    cstate[i] = 0.f;
    xc[i] = floatx4{0.f, 0.f, 0.f, 0.f};
    if (i * NW + w < NT)
      xc[i] = *(const floatx4*)(ch.xin + (long)nl * Gz + (i * NW + w) * 16 + qd * 4);
  }

  for (int t = 0; t < Sz; ++t) {
    if (ch.store_all && t > 0) {
      int pb = (t - 1) & 1;
      int sprev = ch.rev ? (Sz - t) : (t - 1);
#pragma unroll
      for (int it = 0; it < 2; ++it)
        if (hok[it])
          ch.hout[hbase[it] + (long)sprev * Hz] = hfp[pb][hidx[it]];
    }
    if (t + 1 < Sz) {
      const float* xp = ch.xin + (long)(t + 1) * Bz * Gz + (long)nl * Gz;
#pragma unroll
      for (int i = 0; i < TPW; ++i)
        if (i * NW + w < NT)
          xn[i] = *(const floatx4*)(xp + (i * NW + w) * 16 + qd * 4);
    }
    const int rp = t & 1;
    floatx4 acc[TPW];
#pragma unroll
    for (int i = 0; i < TPW; ++i) acc[i] = xc[i];
#pragma unroll
    for (int cc = 0; cc < NCH; ++cc) {
      FragU bhi, blo;
      bhi.v = *(const bf16x8*)(&hhi[rp][nl * HPR + cc * 32 + qd * 8]);
      blo.v = *(const bf16x8*)(&hlo[rp][nl * HPR + cc * 32 + qd * 8]);
#pragma unroll
      for (int i = 0; i < TPW; ++i)
        if (i * NW + w < NT) {
          acc[i] = MFMA(wa[i][cc].v, bhi.v, acc[i]);
          acc[i] = MFMA(wa[i][cc].v, blo.v, acc[i]);
        }
    }
    const int wp = rp ^ 1;
    const bool keep = ch.store_all || (t == Sz - 1);
#pragma unroll
    for (int i = 0; i < TPW; ++i) {
      int tile = i * NW + w;
      if (tile < NT) {
        float cn = sigf(acc[i][1]) * cstate[i] + sigf(acc[i][0]) * tanh_fast(acc[i][2]);
        float h = sigf(acc[i][3]) * tanh_fast(cn);
        cstate[i] = cn;
        int hd = tile * 4 + qd;
        // truncate-split: hi = top 16 bits, lo = exact residual (bf16-trunc)
        unsigned u = __builtin_bit_cast(unsigned, h);
        float hi = __builtin_bit_cast(float, u & 0xFFFF0000u);
        unsigned ul = __builtin_bit_cast(unsigned, h - hi);
        hhi[wp][nl * HPR + hd] = (unsigned short)(u >> 16);
        hlo[wp][nl * HPR + hd] = (unsigned short)(ul >> 16);
        if (keep) hfp[t & 1][nl * Hz + hd] = h;
      }
    }
    barrier_lds_only();
#pragma unroll
    for (int i = 0; i < TPW; ++i) xc[i] = xn[i];
  }
  {
    int pb = (Sz - 1) & 1;
    int slast = ch.rev ? 0 : (Sz - 1);
#pragma unroll
    for (int it = 0; it < 2; ++it)
      if (hok[it])
        ch.hout[hbase[it] + (long)slast * Hz] = hfp[pb][hidx[it]];
  }
}

// ---------------- fused branch: att + feats + match, one kernel ---------------
#define PVS2 102   // padded row stride (floats)
#define FS 104     // feat scratch stride

struct BranchArgs {
  const float* houtA;
  float* mv;
  const float* w_full[4];
  const float* w3; const float* w4; const float* w5; const float* w6;
};

__global__ __launch_bounds__(512, 1) void k_branch(BranchArgs G) {
  __shared__ float pvs[128 * PVS2];
  __shared__ float hvs[128 * PVS2 + 32];   // +pad: feats j+64 lane overread
  __shared__ float wl[60 * PVS2];
  __shared__ float attw[8 * 128];
  __shared__ float fmean[8 * FS];
  __shared__ float fmax[8 * FS];
  __shared__ float nrmp[128], nrmh[128];

  int bx = blockIdx.x;
  int grp = bx >> 6;
  int b = (bx >> 2) & 15;
  int side = (bx >> 1) & 1;
  int rh = bx & 1;
  int fw = !(grp & 1);
  int word = grp < 2;
  int pc = pv_chain(grp);
  const float* PV = G.houtA + (long)pc * HOUT_CH + (long)b * Sz * Hz;
  const float* HV = G.houtA + (long)(pc + 2) * HOUT_CH + (long)b * Sz * Hz;
  int tid = threadIdx.x;
  int w = tid >> 6, lane = tid & 63;

  for (int i = tid; i < 128 * Hz; i += 512) {
    int r = i / Hz, c = i % Hz;
    pvs[r * PVS2 + c] = PV[r * Hz + c];
    hvs[r * PVS2 + c] = HV[r * Hz + c];
  }
  {
    const float* wm = fw ? G.w3 : G.w4;
    const float* wx = fw ? G.w5 : G.w6;
    const float* wf = G.w_full[grp];
    for (int i = tid; i < 60 * Hz; i += 512) {
      int row = i / Hz, c = i % Hz;
      const float* src = (row < 20) ? wf : (row < 40 ? wm : wx);
      int rr = (row < 20) ? row : (row < 40 ? row - 20 : row - 40);
      wl[row * PVS2 + c] = src[rr * Hz + c];
    }
  }
  __syncthreads();
  if (tid < 256) {
    const float* base = (tid < 128) ? pvs : hvs;
    int r = tid & 127;
    float s = 0.f;
    for (int j = 0; j < Hz; ++j) { float v = base[r * PVS2 + j]; s += v * v; }
    if (tid < 128) nrmp[r] = sqrtf(s); else nrmh[r] = sqrtf(s);
  }
  __syncthreads();

  const float* A  = side ? hvs : pvs;
  const float* B  = side ? pvs : hvs;
  const float* nA = side ? nrmh : nrmp;
  const float* nB = side ? nrmp : nrmh;
  int bcrow = fw ? (Sz - 1) : 0;
  float* mvout = G.mv + (long)((word ? 0 : 2) + side) * MV_CH + (long)b * Sz * 120;
  int off = fw ? 0 : 60;
  int type = lane / 20;
  const float* wrow = wl + lane * PVS2;
  float* myatt = attw + w * 128;
  float* myfm = fmean + w * FS;
  float* myfx = fmax + w * FS;

  for (int task = w; task < 64; task += 8) {
    int r = rh * 64 + task;
    const float* ar = A + r * PVS2;
    float d0 = 0.f, d1 = 0.f;
    const float* b0 = B + lane * PVS2;
    const float* b1 = B + (lane + 64) * PVS2;
    for (int j = 0; j < Hz; j += 2) {
      float2 a2 = *(const float2*)(ar + j);
      float2 p2 = *(const float2*)(b0 + j);
      float2 q2 = *(const float2*)(b1 + j);
      d0 += a2.x * p2.x + a2.y * p2.y;
      d1 += a2.x * q2.x + a2.y * q2.y;
    }
    float at0 = d0 * rcpf(fmaxf(nA[r] * nB[lane], EPSV));
    float at1 = d1 * rcpf(fmaxf(nA[r] * nB[lane + 64], EPSV));
    myatt[lane] = at0;
    myatt[lane + 64] = at1;
    float s = at0 + at1;
#pragma unroll
    for (int m = 1; m < 64; m <<= 1) s += __shfl_xor(s, m);
    float inv = rcpf(fmaxf(s, EPSV));
    float m0 = 0.f, m1 = 0.f, x0 = -1e30f, x1 = -1e30f;
    const float* bj0 = B + lane;
    const float* bj1 = B + lane + 64;
    for (int q = 0; q < 128; ++q) {
      float aq = myatt[q];
      float v0 = bj0[q * PVS2];
      float v1 = bj1[q * PVS2];
      m0 += aq * v0; x0 = fmaxf(x0, aq * v0);
      m1 += aq * v1; x1 = fmaxf(x1, aq * v1);
    }
    myfm[lane] = m0 * inv;
    myfx[lane] = x0;
    if (lane < Hz - 64) { myfm[lane + 64] = m1 * inv; myfx[lane + 64] = x1; }
    if (lane < 60) {
      const float* v2p = (type == 0) ? (B + bcrow * PVS2)
                       : (type == 1) ? myfm : myfx;
      float num = 0.f, n1 = 0.f, n2 = 0.f;
      for (int j = 0; j < Hz; j += 2) {
        float2 w2 = *(const float2*)(wrow + j);
        float2 a2 = *(const float2*)(ar + j);
        float2 c2 = *(const float2*)(v2p + j);
        float ws0 = w2.x * w2.x, ws1 = w2.y * w2.y;
        num += ws0 * a2.x * c2.x + ws1 * a2.y * c2.y;
        n1  += ws0 * a2.x * a2.x + ws1 * a2.y * a2.y;
        n2  += ws0 * c2.x * c2.x + ws1 * c2.y * c2.y;
      }
      mvout[r * 120 + off + lane] = num * rcpf(fmaxf(sqrtf(n1) * sqrtf(n2), EPSV));
    }
  }
}

// ---------------- fused head: wave-per-output GEMVs, coalesced ----------------
__global__ __launch_bounds__(1024) void k_head(const float* houtB,
                                               const float* lw, const float* lb,
                                               const float* gw, const float* gb,
                                               const float* f1w, const float* f1b,
                                               const float* f2w, const float* f2b,
                                               float* out) {
  int b = blockIdx.x;
  __shared__ float xr[800];
  __shared__ float hwv[800];
  __shared__ float f1[200];
  int tid = threadIdx.x;
  int w = tid >> 6, lane = tid & 63;
  if (tid < 800) {
    int seq = tid / Gz;
    int i = tid % Gz;
    int seg = i / Hz, j = i % Hz;
    int chain = seq * 4 + seg;
    int s_sel = (seg & 1) ? 0 : (Sz - 1);
    xr[tid] = houtB[((long)chain * Bz + b) * Sz * Hz + (long)s_sel * Hz + j];
  }
  __syncthreads();
  // phase 1: highway. wave per output op (800 = 16 waves x 50). Lanes split
  // K=400 with consecutive-4B reads (coalesced 256B/wave-inst), tree-reduce.
  for (int i = 0; i < 50; ++i) {
    int op = w + 16 * i;              // 0..799
    int seq = op >= Gz;
    int o = op - seq * Gz;
    const float* lwr = lw + (long)o * Gz;
    const float* gwr = gw + (long)o * Gz;
    const float* xs = xr + seq * Gz;
    float al = 0.f, ag = 0.f;
#pragma unroll
    for (int j = 0; j < 7; ++j) {     // 6*64 + 16 = 400
      int k = lane + 64 * j;
      if (j < 6 || lane < 16) {
        float x = xs[k];
        al += x * lwr[k];
        ag += x * gwr[k];
      }
    }
#pragma unroll
    for (int m = 1; m < 64; m <<= 1) {
      al += __shfl_xor(al, m);
      ag += __shfl_xor(ag, m);
    }
    if (lane == 0) {
      al += lb[o];
      ag += gb[o];
      float hlin = fmaxf(al, 0.f);
      float tg = sigf(ag);
      hwv[op] = tg * hlin + (1.f - tg) * xr[op];
    }
  }
  __syncthreads();
  // phase 2: fc1 (200 outputs, K=800 = 12*64 + 32)
  for (int i = 0; i < 13; ++i) {
    int o = w + 16 * i;
    if (o < 200) {
      const float* wr = f1w + (long)o * 800;
      float acc = 0.f;
#pragma unroll
      for (int j = 0; j < 13; ++j) {
        int k = lane + 64 * j;
        if (j < 12 || lane < 32) acc += hwv[k] * wr[k];
      }
#pragma unroll
      for (int m = 1; m < 64; m <<= 1) acc += __shfl_xor(acc, m);
      if (lane == 0) f1[o] = tanh_fast(acc + f1b[o]);
    }
  }
  __syncthreads();
  // phase 3: fc2 (3 outputs, K=200 = 3*64 + 8)
  if (w < 3) {
    const float* wr = f2w + w * 200;
    float acc = 0.f;
#pragma unroll
    for (int j = 0; j < 4; ++j) {
      int k = lane + 64 * j;
      if (j < 3 || lane < 8) acc += f1[k] * wr[k];
    }
#pragma unroll
    for (int m = 1; m < 64; m <<= 1) acc += __shfl_xor(acc, m);
    if (lane == 0) out[b * 3 + w] = acc + f2b[w];
  }
}

// ---------------- host orchestration -----------------------------------------
extern "C" void kernel_launch(void* const* d_in, const int* in_sizes, int n_in,
                              void* d_out, int out_size, void* d_ws, size_t ws_size,
                              hipStream_t stream) {
  (void)in_sizes; (void)n_in; (void)out_size;

  const int* p_ids  = (const int*)d_in[0];
  const int* h_ids  = (const int*)d_in[1];
  const int* cp_ids = (const int*)d_in[2];
  const int* ch_ids = (const int*)d_in[3];
  const float* word_emb = (const float*)d_in[4];
  const float* char_emb = (const float*)d_in[5];
  const float* ctx_Wih_f = (const float*)d_in[6];
  const float* ctx_Whh_f = (const float*)d_in[7];
  const float* ctx_b_f   = (const float*)d_in[8];
  const float* ctx_Wih_b = (const float*)d_in[9];
  const float* ctx_Whh_b = (const float*)d_in[10];
  const float* ctx_b_b   = (const float*)d_in[11];
  const float* chr_Wih_f = (const float*)d_in[12];
  const float* chr_Whh_f = (const float*)d_in[13];
  const float* chr_b_f   = (const float*)d_in[14];
  const float* chr_Wih_b = (const float*)d_in[15];
  const float* chr_Whh_b = (const float*)d_in[16];
  const float* chr_b_b   = (const float*)d_in[17];
  const float* agg_Wih_f = (const float*)d_in[18];
  const float* agg_Whh_f = (const float*)d_in[19];
  const float* agg_b_f   = (const float*)d_in[20];
  const float* agg_Wih_b = (const float*)d_in[21];
  const float* agg_Whh_b = (const float*)d_in[22];
  const float* agg_b_b   = (const float*)d_in[23];
  const float* mp_w1 = (const float*)d_in[24];
  const float* mp_w2 = (const float*)d_in[25];
  const float* mp_w3 = (const float*)d_in[26];
  const float* mp_w4 = (const float*)d_in[27];
  const float* mp_w5 = (const float*)d_in[28];
  const float* mp_w6 = (const float*)d_in[29];
  const float* char_w1 = (const float*)d_in[30];
  const float* char_w2 = (const float*)d_in[31];
  const float* hw_lin_w  = (const float*)d_in[32];
  const float* hw_lin_b  = (const float*)d_in[33];
  const float* hw_gate_w = (const float*)d_in[34];
  const float* hw_gate_b = (const float*)d_in[35];
  const float* fc1_w = (const float*)d_in[36];
  const float* fc1_b = (const float*)d_in[37];
  const float* fc2_w = (const float*)d_in[38];
  const float* fc2_b = (const float*)d_in[39];

  float* ws = (float*)d_ws;
  float* XIN    = ws;                         // 8 * XIN_CH (reused A -> B)
  float* HOUT_A = XIN + 8 * XIN_CH;
  float* HOUT_B = HOUT_A + 8 * HOUT_CH;
  float* MV     = HOUT_B + 8 * HOUT_CH;
  unsigned short* WC = (unsigned short*)(MV + 4 * MV_CH);
  // bf16 W buffers: ctx f/b (KP=320), chr f/b (KP=64), agg f/b (KP=128)
  unsigned short* W_ctx_f = WC;
  unsigned short* W_ctx_b = W_ctx_f + (long)Gz * 320;
  unsigned short* W_chr_f = W_ctx_b + (long)Gz * 320;
  unsigned short* W_chr_b = W_chr_f + (long)Gz * 64;
  unsigned short* W_agg_f = W_chr_b + (long)Gz * 64;
  unsigned short* W_agg_b = W_agg_f + (long)Gz * 128;
  size_t needed = (size_t)((char*)(W_agg_b + (long)Gz * 128) - (char*)ws);
  if (ws_size < needed) return;

  // ---- 0. weight pre-conversion ----
  {
    Cvt6 cv{};
    cv.d[0] = {ctx_Wih_f, W_ctx_f, 300, 320};
    cv.d[1] = {ctx_Wih_b, W_ctx_b, 300, 320};
    cv.d[2] = {chr_Wih_f, W_chr_f, 50, 64};
    cv.d[3] = {chr_Wih_b, W_chr_b, 50, 64};
    cv.d[4] = {agg_Wih_f, W_agg_f, 120, 128};
    cv.d[5] = {agg_Wih_b, W_agg_b, 120, 128};
    k_cvt<<<6 * Gz, 64, 0, stream>>>(cv);
  }
  // ---- 1. fused phase-A projections (block per (chain,t)) ----
  {
    Proj8 pc{};
    const int* idv[8] = {p_ids, p_ids, h_ids, h_ids, cp_ids, cp_ids, ch_ids, ch_ids};
    for (int c = 0; c < 8; ++c) {
      int word = c < 4;
      pc.c[c].ids = idv[c];
      pc.c[c].emb = word ? word_emb : char_emb;
      pc.c[c].src = nullptr;
      pc.c[c].W16  = word ? ((c & 1) ? W_ctx_b : W_ctx_f) : ((c & 1) ? W_chr_b : W_chr_f);
      pc.c[c].bias = word ? ((c & 1) ? ctx_b_b : ctx_b_f) : ((c & 1) ? chr_b_b : chr_b_f);
      pc.c[c].out = XIN + c * XIN_CH;
      pc.c[c].rev = c & 1;
      pc.c[c].K = word ? 300 : 50;
      pc.c[c].nch = word ? 10 : 2;
    }
    k_proj<<<8 * Sz, 256, 0, stream>>>(pc);
  }
  // ---- 2. phase-A LSTMs ----
  {
    Lstm8 la{};
    for (int c = 0; c < 8; ++c) {
      la.c[c].xin = XIN + c * XIN_CH;
      la.c[c].Whh = (c < 4) ? ((c & 1) ? ctx_Whh_b : ctx_Whh_f)
                            : ((c & 1) ? chr_Whh_b : chr_Whh_f);
      la.c[c].hout = HOUT_A + c * HOUT_CH;
      la.c[c].rev = c & 1;
      la.c[c].store_all = 1;
    }
    k_lstm<<<8, 1024, 0, stream>>>(la);
  }
  // ---- 3. fused branch ----
  {
    BranchArgs g{};
    g.houtA = HOUT_A; g.mv = MV;
    g.w_full[0] = mp_w1; g.w_full[1] = mp_w2; g.w_full[2] = char_w1; g.w_full[3] = char_w2;
    g.w3 = mp_w3; g.w4 = mp_w4; g.w5 = mp_w5; g.w6 = mp_w6;
    k_branch<<<256, 512, 0, stream>>>(g);
  }
  // ---- 4. phase-B projections (K=120) ----
  {
    Proj8 pa{};
    for (int c = 0; c < 8; ++c) {
      pa.c[c].ids = nullptr; pa.c[c].emb = nullptr;
      pa.c[c].src = MV + (c >> 1) * MV_CH;
      pa.c[c].W16 = (c & 1) ? W_agg_b : W_agg_f;
      pa.c[c].bias = (c & 1) ? agg_b_b : agg_b_f;
      pa.c[c].out = XIN + c * XIN_CH;
      pa.c[c].rev = c & 1;
      pa.c[c].K = 120;
      pa.c[c].nch = 4;
    }
    k_proj<<<8 * Sz, 256, 0, stream>>>(pa);
  }
  // ---- 5. phase-B LSTMs ----
  {
    Lstm8 la{};
    for (int c = 0; c < 8; ++c) {
      la.c[c].xin = XIN + c * XIN_CH;
      la.c[c].Whh = (c & 1) ? agg_Whh_b : agg_Whh_f;
      la.c[c].hout = HOUT_B + c * HOUT_CH;
      la.c[c].rev = c & 1;
      la.c[c].store_all = 0;
    }
    k_lstm<<<8, 1024, 0, stream>>>(la);
  }
  // ---- 6. fused head ----
  k_head<<<Bz, 1024, 0, stream>>>(HOUT_B, hw_lin_w, hw_lin_b, hw_gate_w, hw_gate_b,
                                  fc1_w, fc1_b, fc2_w, fc2_b, (float*)d_out);
}

// Round 11
// 612.839 us; speedup vs baseline: 1.0868x; 1.0216x over previous
//
#include <hip/hip_runtime.h>

// BiMPM on MI355X. Round 19 (resubmit — round 10 was an infra failure, kernel
// never ran). k_branch is the hidden ~110us (never in top-5; accounting:
// 626 - 2x151 lstm - ~40 proj/cvt/head - ~35 gaps). Issue model: ~44K LDS
// instructions/block x ~6cyc on the one per-CU LDS pipe = ~110us, LDS-bound
// 2x over VALU at 1 block/CU. Cut ~35% of LDS instructions:
// (1) task-pairing (r, r+32): each B[q] read + att broadcast serves 2 tasks
//     (feats 6->3 reads/q, dot 6->4 reads/j-pair);
// (2) feats lane owns j-pair (2l,2l+1) via one b64 read (was 2x b32).
// Per-wave scratch doubles: attw/fmean/fmax -> [16][.]; LDS 141->148KB,
// still 1 block/CU. Element math identical. All other kernels byte-identical
// to round 18 (k_lstm=r16 hfp, k_proj=float4, k_head, k_cvt).

#define Bz 16
#define Sz 128
#define Hz 100
#define Gz 400      // 4H
#define NT 25       // Gz/16 n-tiles
#define EPSV 1e-8f

#define XIN_CH  ((long)Sz * Bz * Gz)    // 819200
#define HOUT_CH ((long)Bz * Sz * Hz)    // 204800
#define MV_CH   ((long)Bz * Sz * 120)   // 245760

typedef __attribute__((ext_vector_type(4))) float floatx4;
typedef __attribute__((ext_vector_type(8))) __bf16 bf16x8;
typedef __attribute__((ext_vector_type(2))) unsigned uintx2;

union FragU { bf16x8 v; unsigned u[4]; unsigned short s[8]; };

__device__ __forceinline__ float bf2f(unsigned short h) {
  unsigned u = ((unsigned)h) << 16;
  return __builtin_bit_cast(float, u);
}
__device__ __forceinline__ unsigned short f2bf(float x) {
  unsigned u = __builtin_bit_cast(unsigned, x);
  u = u + 0x7FFFu + ((u >> 16) & 1u);   // RNE
  return (unsigned short)(u >> 16);
}
__device__ __forceinline__ float rcpf(float x) { return __builtin_amdgcn_rcpf(x); }
__device__ __forceinline__ float sigf(float x) { return rcpf(1.0f + __expf(-x)); }
__device__ __forceinline__ float tanh_fast(float x) {
  return 1.0f - 2.0f * rcpf(__expf(2.0f * x) + 1.0f);
}

// workgroup barrier that does NOT drain vmcnt: LDS-visibility only.
__device__ __forceinline__ void barrier_lds_only() {
  __asm__ __volatile__("s_waitcnt lgkmcnt(0)\ns_barrier" ::: "memory");
}

#define MFMA(a, b, c) __builtin_amdgcn_mfma_f32_16x16x32_bf16((a), (b), (c), 0, 0, 0)

__device__ __forceinline__ int pv_chain(int grp) { return (grp < 2 ? 0 : 4) + (grp & 1); }

// hi/lo truncate-split of 2 floats packed into 2 unsigneds (hi-words)
__device__ __forceinline__ void split2(float a, float b, unsigned& hp, unsigned& lp) {
  unsigned ua = __builtin_bit_cast(unsigned, a);
  unsigned ub = __builtin_bit_cast(unsigned, b);
  hp = (ua >> 16) | (ub & 0xFFFF0000u);
  float ha = __builtin_bit_cast(float, ua & 0xFFFF0000u);
  float hb = __builtin_bit_cast(float, ub & 0xFFFF0000u);
  unsigned la = __builtin_bit_cast(unsigned, a - ha);
  unsigned lb = __builtin_bit_cast(unsigned, b - hb);
  lp = (la >> 16) | (lb & 0xFFFF0000u);
}

// ---------------- weight pre-conversion: fp32 -> bf16, permuted+padded rows ---
// dst row p (p = hidden*4+gate) = src row (p&3)*Hz + (p>>2), padded to KP.
struct CvtDesc { const float* src; unsigned short* dst; int K; int KP; };
struct Cvt6 { CvtDesc d[6]; };

__global__ __launch_bounds__(64) void k_cvt(Cvt6 C) {
  int bx = blockIdx.x;
  int m = bx / Gz;
  int p = bx % Gz;
  CvtDesc d = C.d[m];
  int orig = (p & 3) * Hz + (p >> 2);
  const float* src = d.src + (long)orig * d.K;
  unsigned short* dst = d.dst + (long)p * d.KP;
  for (int k = threadIdx.x; k < d.KP; k += 64)
    dst[k] = (k < d.K) ? f2bf(src[k]) : 0;
}

// ---------------- projection GEMM: block per (chain,t), LDS-staged tokens -----
// out[t][b][p]; W16 = pre-converted bf16, permuted rows, stride KP.
struct ProjChain {
  const int* ids;
  const float* emb;
  const float* src;
  const unsigned short* W16;  // G x KP bf16 (permuted rows, zero-padded)
  const float* bias;          // G fp32 (original order)
  float* out;                 // [t][b][p] fp32, gate-interleaved p
  int rev;
  int K;
  int nch;                    // KP/32
};
struct Proj8 { ProjChain c[8]; };

#define PPS 328   // staged token row stride in ushort

__global__ __launch_bounds__(256) void k_proj(Proj8 P) {
  __shared__ __align__(16) unsigned short phi[16 * PPS];
  __shared__ __align__(16) unsigned short plo[16 * PPS];

  int bx = blockIdx.x;
  int c = bx >> 7;
  int t = bx & 127;
  const ProjChain ch = P.c[c];
  const int K = ch.K;
  const int KP = ch.nch * 32;
  int tp = ch.rev ? (Sz - 1 - t) : t;
  int tid = threadIdx.x;

  // stage tokens: float4 loads (4x fewer latency exposures), b64 LDS writes.
  {
    const int nv = KP >> 2;
    for (int i = tid; i < 16 * nv; i += 256) {
      int b = i / nv;
      int k = (i - b * nv) << 2;
      const float* row = ch.ids ? (ch.emb + (long)ch.ids[b * Sz + tp] * K)
                                : (ch.src + ((long)b * Sz + tp) * K);
      floatx4 v;
      if (k + 3 < K) {
        v = *(const floatx4*)(row + k);
      } else {
        v[0] = (k     < K) ? row[k]     : 0.f;
        v[1] = (k + 1 < K) ? row[k + 1] : 0.f;
        v[2] = (k + 2 < K) ? row[k + 2] : 0.f;
        v[3] = (k + 3 < K) ? row[k + 3] : 0.f;
      }
      unsigned h0, l0, h1, l1;
      split2(v[0], v[1], h0, l0);
      split2(v[2], v[3], h1, l1);
      uintx2 hp, lp;
      hp[0] = h0; hp[1] = h1;
      lp[0] = l0; lp[1] = l1;
      *(uintx2*)&phi[b * PPS + k] = hp;
      *(uintx2*)&plo[b * PPS + k] = lp;
    }
  }
  __syncthreads();

  int w = tid >> 6, lane = tid & 63;
  int nl = lane & 15, qd = lane >> 4;
  floatx4 acc[7];
#pragma unroll
  for (int i = 0; i < 7; ++i) acc[i] = floatx4{0.f, 0.f, 0.f, 0.f};

  // per-tile W row bases (hoisted)
  const unsigned short* wbase[7];
#pragma unroll
  for (int i = 0; i < 7; ++i) {
    int nt = w + 4 * i;
    wbase[i] = (nt < NT) ? (ch.W16 + (long)(nt * 16 + nl) * KP) : ch.W16;
  }

  for (int cc = 0; cc < ch.nch; ++cc) {
    FragU bhi, blo;
    bhi.v = *(const bf16x8*)&phi[nl * PPS + cc * 32 + qd * 8];
    blo.v = *(const bf16x8*)&plo[nl * PPS + cc * 32 + qd * 8];
    int ko = cc * 32 + qd * 8;
#pragma unroll
    for (int i = 0; i < 7; ++i) {
      if (w + 4 * i < NT) {
        FragU whi;
        whi.v = *(const bf16x8*)(wbase[i] + ko);
        acc[i] = MFMA(whi.v, bhi.v, acc[i]);
        acc[i] = MFMA(whi.v, blo.v, acc[i]);
      }
    }
  }
#pragma unroll
  for (int i = 0; i < 7; ++i) {
    int nt = w + 4 * i;
    if (nt < NT) {
#pragma unroll
      for (int r = 0; r < 4; ++r) {
        int p = nt * 16 + qd * 4 + r;
        acc[i][r] += ch.bias[(p & 3) * Hz + (p >> 2)];
      }
      *(floatx4*)(ch.out + ((long)t * Bz + nl) * Gz + nt * 16 + qd * 4) = acc[i];
    }
  }
}

// ---------------- LSTM scan: one workgroup (16 waves) per chain ---------------
struct LstmChain {
  const float* xin;     // [t][b][p] gate-interleaved
  const float* Whh;     // G x H fp32 (original row order)
  float* hout;          // B x S x H fp32
  int rev;
  int store_all;
};
struct Lstm8 { LstmChain c[8]; };

#define NW 16     // waves per block
#define TPW 2     // max tiles per wave; tile = i*NW + w
#define NCH 4     // K chunks of 32 (K=128 padded, valid 100)
#define HPR 136   // plane row stride in halfwords (272B; 4(nl+qd) mod 32 even)

__global__ __launch_bounds__(1024, 4) void k_lstm(Lstm8 P) {
  __shared__ __align__(16) unsigned short hhi[2][Bz * HPR];  // bf16 hi plane
  __shared__ __align__(16) unsigned short hlo[2][Bz * HPR];  // bf16 lo plane
  __shared__ float hfp[2][Bz * Hz];                          // fp32 h stage

  const LstmChain ch = P.c[blockIdx.x];
  const int tid = threadIdx.x;
  const int w = tid >> 6;
  const int lane = tid & 63;
  const int nl = lane & 15;
  const int qd = lane >> 4;

  // zero both planes (padding k=100..127 stays 0 forever)
  for (int i = tid; i < Bz * HPR; i += 1024) {
    ((unsigned*)hhi)[i] = 0;
    ((unsigned*)hlo)[i] = 0;
  }
  __syncthreads();

  // Whh fragments: plain bf16, k = cc*32 + qd*8 + j (k_proj layout)
  FragU wa[TPW][NCH];
#pragma unroll
  for (int i = 0; i < TPW; ++i) {
    int tile = i * NW + w;
    if (tile < NT) {
      int pA = tile * 16 + nl;
      const float* wr = ch.Whh + (long)((pA & 3) * Hz + (pA >> 2)) * Hz;
#pragma unroll
      for (int cc = 0; cc < NCH; ++cc) {
#pragma unroll
        for (int j = 0; j < 8; ++j) {
          int k = cc * 32 + qd * 8 + j;
          wa[i][cc].s[j] = f2bf((k < Hz) ? wr[k] : 0.f);
        }
      }
    }
  }

  // hout store addressing hoisted (idx = tid + it*1024)
  long hbase[2]; int hok[2]; int hidx[2];
#pragma unroll
  for (int it = 0; it < 2; ++it) {
    int idx = tid + it * 1024;
    hok[it] = idx < Bz * Hz;
    int bq = idx / Hz, rq = idx - bq * Hz;
    hbase[it] = (long)bq * Sz * Hz + rq;
    hidx[it] = idx;
  }

  floatx4 xc[TPW], xn[TPW];
  float cstate[TPW];
#pragma unroll
  for (int i = 0; i < TPW; ++i) {
    cstate[i] = 0.f;
    xc[i] = floatx4{0.f, 0.f, 0.f, 0.f};
    if (i * NW + w < NT)
      xc[i] = *(const floatx4*)(ch.xin + (long)nl * Gz + (i * NW + w) * 16 + qd * 4);
  }

  for (int t = 0; t < Sz; ++t) {
    if (ch.store_all && t > 0) {
      int pb = (t - 1) & 1;
      int sprev = ch.rev ? (Sz - t) : (t - 1);
#pragma unroll
      for (int it = 0; it < 2; ++it)
        if (hok[it])
          ch.hout[hbase[it] + (long)sprev * Hz] = hfp[pb][hidx[it]];
    }
    if (t + 1 < Sz) {
      const float* xp = ch.xin + (long)(t + 1) * Bz * Gz + (long)nl * Gz;
#pragma unroll
      for (int i = 0; i < TPW; ++i)
        if (i * NW + w < NT)
          xn[i] = *(const floatx4*)(xp + (i * NW + w) * 16 + qd * 4);
    }
    const int rp = t & 1;
    floatx4 acc[TPW];
#pragma unroll
    for (int i = 0; i < TPW; ++i) acc[i] = xc[i];
#pragma unroll
    for (int cc = 0; cc < NCH; ++cc) {
      FragU bhi, blo;
      bhi.v = *(const bf16x8*)(&hhi[rp][nl * HPR + cc * 32 + qd * 8]);
      blo.v = *(const bf16x8*)(&hlo[rp][nl * HPR + cc * 32 + qd * 8]);
#pragma unroll
      for (int i = 0; i < TPW; ++i)
        if (i * NW + w < NT) {
          acc[i] = MFMA(wa[i][cc].v, bhi.v, acc[i]);
          acc[i] = MFMA(wa[i][cc].v, blo.v, acc[i]);
        }
    }
    const int wp = rp ^ 1;
    const bool keep = ch.store_all || (t == Sz - 1);
#pragma unroll
    for (int i = 0; i < TPW; ++i) {
      int tile = i * NW + w;
      if (tile < NT) {
        float cn = sigf(acc[i][1]) * cstate[i] + sigf(acc[i][0]) * tanh_fast(acc[i][2]);
        float h = sigf(acc[i][3]) * tanh_fast(cn);
        cstate[i] = cn;
        int hd = tile * 4 + qd;
        // truncate-split: hi = top 16 bits, lo = exact residual (bf16-trunc)
        unsigned u = __builtin_bit_cast(unsigned, h);
        float hi = __builtin_bit_cast(float, u & 0xFFFF0000u);
        unsigned ul = __builtin_bit_cast(unsigned, h - hi);
        hhi[wp][nl * HPR + hd] = (unsigned short)(u >> 16);
        hlo[wp][nl * HPR + hd] = (unsigned short)(ul >> 16);
        if (keep) hfp[t & 1][nl * Hz + hd] = h;
      }
    }
    barrier_lds_only();
#pragma unroll
    for (int i = 0; i < TPW; ++i) xc[i] = xn[i];
  }
  {
    int pb = (Sz - 1) & 1;
    int slast = ch.rev ? 0 : (Sz - 1);
#pragma unroll
    for (int it = 0; it < 2; ++it)
      if (hok[it])
        ch.hout[hbase[it] + (long)slast * Hz] = hfp[pb][hidx[it]];
  }
}

// ---------------- fused branch: att + feats + match, task-paired -------------
#define PVS2 102   // padded row stride (floats)
#define FS 104     // feat scratch stride

struct BranchArgs {
  const float* houtA;
  float* mv;
  const float* w_full[4];
  const float* w3; const float* w4; const float* w5; const float* w6;
};

__global__ __launch_bounds__(512, 1) void k_branch(BranchArgs G) {
  __shared__ float pvs[128 * PVS2];
  __shared__ float hvs[128 * PVS2 + 32];   // +pad: feats lane overread
  __shared__ float wl[60 * PVS2];
  __shared__ float attw[16 * 128];         // per-wave 2 tasks
  __shared__ float fmean[16 * FS];
  __shared__ float fmax[16 * FS];
  __shared__ float nrmp[128], nrmh[128];

  int bx = blockIdx.x;
  int grp = bx >> 6;
  int b = (bx >> 2) & 15;
  int side = (bx >> 1) & 1;
  int rh = bx & 1;
  int fw = !(grp & 1);
  int word = grp < 2;
  int pc = pv_chain(grp);
  const float* PV = G.houtA + (long)pc * HOUT_CH + (long)b * Sz * Hz;
  const float* HV = G.houtA + (long)(pc + 2) * HOUT_CH + (long)b * Sz * Hz;
  int tid = threadIdx.x;
  int w = tid >> 6, lane = tid & 63;

  for (int i = tid; i < 128 * Hz; i += 512) {
    int r = i / Hz, c = i % Hz;
    pvs[r * PVS2 + c] = PV[r * Hz + c];
    hvs[r * PVS2 + c] = HV[r * Hz + c];
  }
  {
    const float* wm = fw ? G.w3 : G.w4;
    const float* wx = fw ? G.w5 : G.w6;
    const float* wf = G.w_full[grp];
    for (int i = tid; i < 60 * Hz; i += 512) {
      int row = i / Hz, c = i % Hz;
      const float* src = (row < 20) ? wf : (row < 40 ? wm : wx);
      int rr = (row < 20) ? row : (row < 40 ? row - 20 : row - 40);
      wl[row * PVS2 + c] = src[rr * Hz + c];
    }
  }
  __syncthreads();
  if (tid < 256) {
    const float* base = (tid < 128) ? pvs : hvs;
    int r = tid & 127;
    float s = 0.f;
    for (int j = 0; j < Hz; ++j) { float v = base[r * PVS2 + j]; s += v * v; }
    if (tid < 128) nrmp[r] = sqrtf(s); else nrmh[r] = sqrtf(s);
  }
  __syncthreads();

  const float* A  = side ? hvs : pvs;
  const float* B  = side ? pvs : hvs;
  const float* nA = side ? nrmh : nrmp;
  const float* nB = side ? nrmp : nrmh;
  int bcrow = fw ? (Sz - 1) : 0;
  float* mvout = G.mv + (long)((word ? 0 : 2) + side) * MV_CH + (long)b * Sz * 120;
  int off = fw ? 0 : 60;
  int type = lane / 20;
  const float* wrow = wl + lane * PVS2;
  float* myattA = attw + (w * 2 + 0) * 128;
  float* myattB = attw + (w * 2 + 1) * 128;
  float* myfmA = fmean + (w * 2 + 0) * FS;
  float* myfmB = fmean + (w * 2 + 1) * FS;
  float* myfxA = fmax + (w * 2 + 0) * FS;
  float* myfxB = fmax + (w * 2 + 1) * FS;

  const float* b0 = B + lane * PVS2;
  const float* b1 = B + (lane + 64) * PVS2;
  const float* bj = B + 2 * lane;

  for (int i = 0; i < 4; ++i) {
    int rA = rh * 64 + w + 8 * i;
    int rB = rA + 32;
    const float* arA = A + rA * PVS2;
    const float* arB = A + rB * PVS2;
    // paired dots: B rows read once for both tasks
    float d0A = 0.f, d1A = 0.f, d0B = 0.f, d1B = 0.f;
    for (int j = 0; j < Hz; j += 2) {
      float2 aA = *(const float2*)(arA + j);
      float2 aB = *(const float2*)(arB + j);
      float2 p2 = *(const float2*)(b0 + j);
      float2 q2 = *(const float2*)(b1 + j);
      d0A += aA.x * p2.x + aA.y * p2.y;
      d1A += aA.x * q2.x + aA.y * q2.y;
      d0B += aB.x * p2.x + aB.y * p2.y;
      d1B += aB.x * q2.x + aB.y * q2.y;
    }
    float atA0 = d0A * rcpf(fmaxf(nA[rA] * nB[lane], EPSV));
    float atA1 = d1A * rcpf(fmaxf(nA[rA] * nB[lane + 64], EPSV));
    float atB0 = d0B * rcpf(fmaxf(nA[rB] * nB[lane], EPSV));
    float atB1 = d1B * rcpf(fmaxf(nA[rB] * nB[lane + 64], EPSV));
    myattA[lane] = atA0; myattA[lane + 64] = atA1;
    myattB[lane] = atB0; myattB[lane + 64] = atB1;
    float sA = atA0 + atA1, sB = atB0 + atB1;
#pragma unroll
    for (int m = 1; m < 64; m <<= 1) {
      sA += __shfl_xor(sA, m);
      sB += __shfl_xor(sB, m);
    }
    float invA = rcpf(fmaxf(sA, EPSV));
    float invB = rcpf(fmaxf(sB, EPSV));
    // paired feats: lane owns j-pair (2l, 2l+1); one b64 B read serves both
    if (lane < Hz / 2) {
      float2 mA{0.f, 0.f}, mB{0.f, 0.f};
      float2 xA{-1e30f, -1e30f}, xB{-1e30f, -1e30f};
      for (int q = 0; q < 128; ++q) {
        float2 v = *(const float2*)(bj + q * PVS2);
        float aA = myattA[q], aB = myattB[q];
        float pAx = aA * v.x, pAy = aA * v.y;
        float pBx = aB * v.x, pBy = aB * v.y;
        mA.x += pAx; mA.y += pAy;
        mB.x += pBx; mB.y += pBy;
        xA.x = fmaxf(xA.x, pAx); xA.y = fmaxf(xA.y, pAy);
        xB.x = fmaxf(xB.x, pBx); xB.y = fmaxf(xB.y, pBy);
      }
      *(float2*)&myfmA[2 * lane] = float2{mA.x * invA, mA.y * invA};
      *(float2*)&myfxA[2 * lane] = xA;
      *(float2*)&myfmB[2 * lane] = float2{mB.x * invB, mB.y * invB};
      *(float2*)&myfxB[2 * lane] = xB;
    }
    // match for both tasks
    if (lane < 60) {
#pragma unroll
      for (int s = 0; s < 2; ++s) {
        int r = s ? rB : rA;
        const float* ar = s ? arB : arA;
        const float* fm = s ? myfmB : myfmA;
        const float* fx = s ? myfxB : myfxA;
        const float* v2p = (type == 0) ? (B + bcrow * PVS2)
                         : (type == 1) ? fm : fx;
        float num = 0.f, n1 = 0.f, n2 = 0.f;
        for (int j = 0; j < Hz; j += 2) {
          float2 w2 = *(const float2*)(wrow + j);
          float2 a2 = *(const float2*)(ar + j);
          float2 c2 = *(const float2*)(v2p + j);
          float ws0 = w2.x * w2.x, ws1 = w2.y * w2.y;
          num += ws0 * a2.x * c2.x + ws1 * a2.y * c2.y;
          n1  += ws0 * a2.x * a2.x + ws1 * a2.y * a2.y;
          n2  += ws0 * c2.x * c2.x + ws1 * c2.y * c2.y;
        }
        mvout[r * 120 + off + lane] = num * rcpf(fmaxf(sqrtf(n1) * sqrtf(n2), EPSV));
      }
    }
  }
}

// ---------------- fused head: wave-per-output GEMVs, coalesced ----------------
__global__ __launch_bounds__(1024) void k_head(const float* houtB,
                                               const float* lw, const float* lb,
                                               const float* gw, const float* gb,
                                               const float* f1w, const float* f1b,
                                               const float* f2w, const float* f2b,
                                               float* out) {
  int b = blockIdx.x;
  __shared__ float xr[800];
  __shared__ float hwv[800];
  __shared__ float f1[200];
  int tid = threadIdx.x;
  int w = tid >> 6, lane = tid & 63;
  if (tid < 800) {
    int seq = tid / Gz;
    int i = tid % Gz;
    int seg = i / Hz, j = i % Hz;
    int chain = seq * 4 + seg;
    int s_sel = (seg & 1) ? 0 : (Sz - 1);
    xr[tid] = houtB[((long)chain * Bz + b) * Sz * Hz + (long)s_sel * Hz + j];
  }
  __syncthreads();
  // phase 1: highway. wave per output op (800 = 16 waves x 50). Lanes split
  // K=400 with consecutive-4B reads (coalesced 256B/wave-inst), tree-reduce.
  for (int i = 0; i < 50; ++i) {
    int op = w + 16 * i;              // 0..799
    int seq = op >= Gz;
    int o = op - seq * Gz;
    const float* lwr = lw + (long)o * Gz;
    const float* gwr = gw + (long)o * Gz;
    const float* xs = xr + seq * Gz;
    float al = 0.f, ag = 0.f;
#pragma unroll
    for (int j = 0; j < 7; ++j) {     // 6*64 + 16 = 400
      int k = lane + 64 * j;
      if (j < 6 || lane < 16) {
        float x = xs[k];
        al += x * lwr[k];
        ag += x * gwr[k];
      }
    }
#pragma unroll
    for (int m = 1; m < 64; m <<= 1) {
      al += __shfl_xor(al, m);
      ag += __shfl_xor(ag, m);
    }
    if (lane == 0) {
      al += lb[o];
      ag += gb[o];
      float hlin = fmaxf(al, 0.f);
      float tg = sigf(ag);
      hwv[op] = tg * hlin + (1.f - tg) * xr[op];
    }
  }
  __syncthreads();
  // phase 2: fc1 (200 outputs, K=800 = 12*64 + 32)
  for (int i = 0; i < 13; ++i) {
    int o = w + 16 * i;
    if (o < 200) {
      const float* wr = f1w + (long)o * 800;
      float acc = 0.f;
#pragma unroll
      for (int j = 0; j < 13; ++j) {
        int k = lane + 64 * j;
        if (j < 12 || lane < 32) acc += hwv[k] * wr[k];
      }
#pragma unroll
      for (int m = 1; m < 64; m <<= 1) acc += __shfl_xor(acc, m);
      if (lane == 0) f1[o] = tanh_fast(acc + f1b[o]);
    }
  }
  __syncthreads();
  // phase 3: fc2 (3 outputs, K=200 = 3*64 + 8)
  if (w < 3) {
    const float* wr = f2w + w * 200;
    float acc = 0.f;
#pragma unroll
    for (int j = 0; j < 4; ++j) {
      int k = lane + 64 * j;
      if (j < 3 || lane < 8) acc += f1[k] * wr[k];
    }
#pragma unroll
    for (int m = 1; m < 64; m <<= 1) acc += __shfl_xor(acc, m);
    if (lane == 0) out[b * 3 + w] = acc + f2b[w];
  }
}

// ---------------- host orchestration -----------------------------------------
extern "C" void kernel_launch(void* const* d_in, const int* in_sizes, int n_in,
                              void* d_out, int out_size, void* d_ws, size_t ws_size,
                              hipStream_t stream) {
  (void)in_sizes; (void)n_in; (void)out_size;

  const int* p_ids  = (const int*)d_in[0];
  const int* h_ids  = (const int*)d_in[1];
  const int* cp_ids = (const int*)d_in[2];
  const int* ch_ids = (const int*)d_in[3];
  const float* word_emb = (const float*)d_in[4];
  const float* char_emb = (const float*)d_in[5];
  const float* ctx_Wih_f = (const float*)d_in[6];
  const float* ctx_Whh_f = (const float*)d_in[7];
  const float* ctx_b_f   = (const float*)d_in[8];
  const float* ctx_Wih_b = (const float*)d_in[9];
  const float* ctx_Whh_b = (const float*)d_in[10];
  const float* ctx_b_b   = (const float*)d_in[11];
  const float* chr_Wih_f = (const float*)d_in[12];
  const float* chr_Whh_f = (const float*)d_in[13];
  const float* chr_b_f   = (const float*)d_in[14];
  const float* chr_Wih_b = (const float*)d_in[15];
  const float* chr_Whh_b = (const float*)d_in[16];
  const float* chr_b_b   = (const float*)d_in[17];
  const float* agg_Wih_f = (const float*)d_in[18];
  const float* agg_Whh_f = (const float*)d_in[19];
  const float* agg_b_f   = (const float*)d_in[20];
  const float* agg_Wih_b = (const float*)d_in[21];
  const float* agg_Whh_b = (const float*)d_in[22];
  const float* agg_b_b   = (const float*)d_in[23];
  const float* mp_w1 = (const float*)d_in[24];
  const float* mp_w2 = (const float*)d_in[25];
  const float* mp_w3 = (const float*)d_in[26];
  const float* mp_w4 = (const float*)d_in[27];
  const float* mp_w5 = (const float*)d_in[28];
  const float* mp_w6 = (const float*)d_in[29];
  const float* char_w1 = (const float*)d_in[30];
  const float* char_w2 = (const float*)d_in[31];
  const float* hw_lin_w  = (const float*)d_in[32];
  const float* hw_lin_b  = (const float*)d_in[33];
  const float* hw_gate_w = (const float*)d_in[34];
  const float* hw_gate_b = (const float*)d_in[35];
  const float* fc1_w = (const float*)d_in[36];
  const float* fc1_b = (const float*)d_in[37];
  const float* fc2_w = (const float*)d_in[38];
  const float* fc2_b = (const float*)d_in[39];

  float* ws = (float*)d_ws;
  float* XIN    = ws;                         // 8 * XIN_CH (reused A -> B)
  float* HOUT_A = XIN + 8 * XIN_CH;
  float* HOUT_B = HOUT_A + 8 * HOUT_CH;
  float* MV     = HOUT_B + 8 * HOUT_CH;
  unsigned short* WC = (unsigned short*)(MV + 4 * MV_CH);
  // bf16 W buffers: ctx f/b (KP=320), chr f/b (KP=64), agg f/b (KP=128)
  unsigned short* W_ctx_f = WC;
  unsigned short* W_ctx_b = W_ctx_f + (long)Gz * 320;
  unsigned short* W_chr_f = W_ctx_b + (long)Gz * 320;
  unsigned short* W_chr_b = W_chr_f + (long)Gz * 64;
  unsigned short* W_agg_f = W_chr_b + (long)Gz * 64;
  unsigned short* W_agg_b = W_agg_f + (long)Gz * 128;
  size_t needed = (size_t)((char*)(W_agg_b + (long)Gz * 128) - (char*)ws);
  if (ws_size < needed) return;

  // ---- 0. weight pre-conversion ----
  {
    Cvt6 cv{};
    cv.d[0] = {ctx_Wih_f, W_ctx_f, 300, 320};
    cv.d[1] = {ctx_Wih_b, W_ctx_b, 300, 320};
    cv.d[2] = {chr_Wih_f, W_chr_f, 50, 64};
    cv.d[3] = {chr_Wih_b, W_chr_b, 50, 64};
    cv.d[4] = {agg_Wih_f, W_agg_f, 120, 128};
    cv.d[5] = {agg_Wih_b, W_agg_b, 120, 128};
    k_cvt<<<6 * Gz, 64, 0, stream>>>(cv);
  }
  // ---- 1. fused phase-A projections (block per (chain,t)) ----
  {
    Proj8 pc{};
    const int* idv[8] = {p_ids, p_ids, h_ids, h_ids, cp_ids, cp_ids, ch_ids, ch_ids};
    for (int c = 0; c < 8; ++c) {
      int word = c < 4;
      pc.c[c].ids = idv[c];
      pc.c[c].emb = word ? word_emb : char_emb;
      pc.c[c].src = nullptr;
      pc.c[c].W16  = word ? ((c & 1) ? W_ctx_b : W_ctx_f) : ((c & 1) ? W_chr_b : W_chr_f);
      pc.c[c].bias = word ? ((c & 1) ? ctx_b_b : ctx_b_f) : ((c & 1) ? chr_b_b : chr_b_f);
      pc.c[c].out = XIN + c * XIN_CH;
      pc.c[c].rev = c & 1;
      pc.c[c].K = word ? 300 : 50;
      pc.c[c].nch = word ? 10 : 2;
    }
    k_proj<<<8 * Sz, 256, 0, stream>>>(pc);
  }
  // ---- 2. phase-A LSTMs ----
  {
    Lstm8 la{};
    for (int c = 0; c < 8; ++c) {
      la.c[c].xin = XIN + c * XIN_CH;
      la.c[c].Whh = (c < 4) ? ((c & 1) ? ctx_Whh_b : ctx_Whh_f)
                            : ((c & 1) ? chr_Whh_b : chr_Whh_f);
      la.c[c].hout = HOUT_A + c * HOUT_CH;
      la.c[c].rev = c & 1;
      la.c[c].store_all = 1;
    }
    k_lstm<<<8, 1024, 0, stream>>>(la);
  }
  // ---- 3. fused branch ----
  {
    BranchArgs g{};
    g.houtA = HOUT_A; g.mv = MV;
    g.w_full[0] = mp_w1; g.w_full[1] = mp_w2; g.w_full[2] = char_w1; g.w_full[3] = char_w2;
    g.w3 = mp_w3; g.w4 = mp_w4; g.w5 = mp_w5; g.w6 = mp_w6;
    k_branch<<<256, 512, 0, stream>>>(g);
  }
  // ---- 4. phase-B projections (K=120) ----
  {
    Proj8 pa{};
    for (int c = 0; c < 8; ++c) {
      pa.c[c].ids = nullptr; pa.c[c].emb = nullptr;
      pa.c[c].src = MV + (c >> 1) * MV_CH;
      pa.c[c].W16 = (c & 1) ? W_agg_b : W_agg_f;
      pa.c[c].bias = (c & 1) ? agg_b_b : agg_b_f;
      pa.c[c].out = XIN + c * XIN_CH;
      pa.c[c].rev = c & 1;
      pa.c[c].K = 120;
      pa.c[c].nch = 4;
    }
    k_proj<<<8 * Sz, 256, 0, stream>>>(pa);
  }
  // ---- 5. phase-B LSTMs ----
  {
    Lstm8 la{};
    for (int c = 0; c < 8; ++c) {
      la.c[c].xin = XIN + c * XIN_CH;
      la.c[c].Whh = (c & 1) ? agg_Whh_b : agg_Whh_f;
      la.c[c].hout = HOUT_B + c * HOUT_CH;
      la.c[c].rev = c & 1;
      la.c[c].store_all = 0;
    }
    k_lstm<<<8, 1024, 0, stream>>>(la);
  }
  // ---- 6. fused head ----
  k_head<<<Bz, 1024, 0, stream>>>(HOUT_B, hw_lin_w, hw_lin_b, hw_gate_w, hw_gate_b,
                                  fc1_w, fc1_b, fc2_w, fc2_b, (float*)d_out);
}